// Round 3
// baseline (597.095 us; speedup 1.0000x reference)
//
#include <hip/hip_runtime.h>

#define BATCH 4096
#define NF 128
#define NW 128
#define NO 32
#define MT 64     // batch rows per block; 16 rows per wave (wave-private end-to-end)
#define LDH 136   // h plane stride in u16 (272B rows, 16B-aligned)

// d_ws layout (u16 elements): wh_hi | wh_lo | wo_hi | wo_lo
#define WH_ELEMS (2 * 128 * 128 * 128)  // 4,194,304
#define WO_ELEMS (128 * 128 * 32)       //   524,288
// total ws bytes = (2*WH + 2*WO)*2 = 18,874,368

typedef __bf16 bf16x8 __attribute__((ext_vector_type(8)));
typedef float f32x4 __attribute__((ext_vector_type(4)));

static __device__ __forceinline__ unsigned short f2bf(float f) {
    unsigned u = __builtin_bit_cast(unsigned, f);
    u += 0x7FFFu + ((u >> 16) & 1u);  // RNE
    return (unsigned short)(u >> 16);
}
static __device__ __forceinline__ float bf2f(unsigned short h) {
    return __builtin_bit_cast(float, ((unsigned)h) << 16);
}

__global__ void zero_out_kernel(float* __restrict__ out, int n) {
    int i = blockIdx.x * blockDim.x + threadIdx.x;
    if (i < n) out[i] = 0.0f;
}

// Transpose + hi/lo split weights into ws. One element-pair per thread.
__global__ void prep_weights(const float* __restrict__ Wh, const float* __restrict__ Wo,
                             unsigned short* __restrict__ ws) {
    unsigned short* wh_hi = ws;
    unsigned short* wh_lo = ws + WH_ELEMS;
    unsigned short* wo_hi = ws + 2 * WH_ELEMS;
    unsigned short* wo_lo = ws + 2 * WH_ELEMS + WO_ELEMS;
    int t = blockIdx.x * blockDim.x + threadIdx.x;
    if (t < WH_ELEMS / 2) {
        int kp = t & 63;            // k-pair
        int v  = (t >> 6) & 127;    // output col
        int lf = t >> 13;           // l*128+f
        size_t s = (size_t)lf * 16384;
        float g0 = Wh[s + (size_t)(2 * kp) * 128 + v];      // Wh[l,f,k,v]
        float g1 = Wh[s + (size_t)(2 * kp + 1) * 128 + v];
        unsigned short h0 = f2bf(g0), h1 = f2bf(g1);
        unsigned short l0 = f2bf(g0 - bf2f(h0)), l1 = f2bf(g1 - bf2f(h1));
        size_t d = s + (size_t)v * 128 + 2 * kp;            // Wt[l,f,v,k]
        *(unsigned*)&wh_hi[d] = (unsigned)h0 | ((unsigned)h1 << 16);
        *(unsigned*)&wh_lo[d] = (unsigned)l0 | ((unsigned)l1 << 16);
    }
    if (t < WO_ELEMS / 2) {
        int kp = t & 63;
        int o  = (t >> 6) & 31;
        int f  = t >> 11;
        size_t s = (size_t)f * 4096;
        float g0 = Wo[s + (size_t)(2 * kp) * 32 + o];       // Wo[f,k,o]
        float g1 = Wo[s + (size_t)(2 * kp + 1) * 32 + o];
        unsigned short h0 = f2bf(g0), h1 = f2bf(g1);
        unsigned short l0 = f2bf(g0 - bf2f(h0)), l1 = f2bf(g1 - bf2f(h1));
        size_t d = s + (size_t)o * 128 + 2 * kp;            // WoT[f,o,k]
        *(unsigned*)&wo_hi[d] = (unsigned)h0 | ((unsigned)h1 << 16);
        *(unsigned*)&wo_lo[d] = (unsigned)l0 | ((unsigned)l1 << 16);
    }
}

// Fused MLP chain. Each wave owns 16 batch rows end-to-end: NO barriers anywhere.
__global__ __launch_bounds__(256, 3) void ngam_fused(
    const float* __restrict__ x, const float* __restrict__ W1,
    const float* __restrict__ b1, const float* __restrict__ bh,
    const float* __restrict__ bo, const unsigned short* __restrict__ ws,
    float* __restrict__ out) {
    __shared__ unsigned short h_hi[MT * LDH];
    __shared__ unsigned short h_lo[MT * LDH];
    const unsigned short* wh_hi = ws;
    const unsigned short* wh_lo = ws + WH_ELEMS;
    const unsigned short* wo_hi = ws + 2 * WH_ELEMS;
    const unsigned short* wo_lo = ws + 2 * WH_ELEMS + WO_ELEMS;

    const int f    = blockIdx.x >> 6;
    const int m0   = (blockIdx.x & 63) * MT;
    const int tid  = threadIdx.x;
    const int wave = tid >> 6;
    const int lane = tid & 63;
    const int arow = lane & 15;  // A row / B col / C col
    const int kgrp = lane >> 4;  // k-group; C row-group
    const int r0   = wave * 16;  // this wave's private rows

    // ---- layer 0: rows m = tid>>2 lie in [r0, r0+16) -> wave-private ----
    {
        int m = tid >> 2, c = tid & 3;
        float xv = x[(size_t)(m0 + m) * NF + f];
        for (int j = 0; j < 8; ++j) {
            int wq = c * 32 + j * 4;
            float4 w1 = *(const float4*)&W1[f * NW + wq];
            float4 bb = *(const float4*)&b1[f * NW + wq];
            float v0 = fmaxf(xv * w1.x + bb.x, 0.0f);
            float v1 = fmaxf(xv * w1.y + bb.y, 0.0f);
            float v2 = fmaxf(xv * w1.z + bb.z, 0.0f);
            float v3 = fmaxf(xv * w1.w + bb.w, 0.0f);
            unsigned short a0 = f2bf(v0), a1 = f2bf(v1), a2 = f2bf(v2), a3 = f2bf(v3);
            unsigned short c0 = f2bf(v0 - bf2f(a0)), c1 = f2bf(v1 - bf2f(a1));
            unsigned short c2 = f2bf(v2 - bf2f(a2)), c3 = f2bf(v3 - bf2f(a3));
            *(unsigned*)&h_hi[m * LDH + wq]     = (unsigned)a0 | ((unsigned)a1 << 16);
            *(unsigned*)&h_hi[m * LDH + wq + 2] = (unsigned)a2 | ((unsigned)a3 << 16);
            *(unsigned*)&h_lo[m * LDH + wq]     = (unsigned)c0 | ((unsigned)c1 << 16);
            *(unsigned*)&h_lo[m * LDH + wq + 2] = (unsigned)c2 | ((unsigned)c3 << 16);
        }
    }

    // ---- hidden layers ----
    for (int l = 0; l < 2; ++l) {
        const int wbase = (l * NF + f) * 16384;  // u16 elems
        const float* bhl = bh + ((size_t)l * NF + f) * NW;
        f32x4 acc[8];
        for (int nt = 0; nt < 8; ++nt) {
            float bv = bhl[nt * 16 + arow];
            acc[nt] = (f32x4){bv, bv, bv, bv};
        }
        for (int kt = 0; kt < 4; ++kt) {
            const int kof = kt * 32 + kgrp * 8;
            bf16x8 a_hi = *(const bf16x8*)&h_hi[(r0 + arow) * LDH + kof];
            bf16x8 a_lo = *(const bf16x8*)&h_lo[(r0 + arow) * LDH + kof];
            for (int nt = 0; nt < 8; ++nt) {
                const int boff = wbase + (nt * 16 + arow) * 128 + kof;
                bf16x8 b_hi = *(const bf16x8*)&wh_hi[boff];
                bf16x8 b_lo = *(const bf16x8*)&wh_lo[boff];
                acc[nt] = __builtin_amdgcn_mfma_f32_16x16x32_bf16(a_hi, b_hi, acc[nt], 0, 0, 0);
                acc[nt] = __builtin_amdgcn_mfma_f32_16x16x32_bf16(a_lo, b_hi, acc[nt], 0, 0, 0);
                acc[nt] = __builtin_amdgcn_mfma_f32_16x16x32_bf16(a_hi, b_lo, acc[nt], 0, 0, 0);
            }
        }
        // relu + split writeback; rows [r0, r0+16) wave-private
        for (int nt = 0; nt < 8; ++nt)
            for (int r = 0; r < 4; ++r) {
                int row = r0 + kgrp * 4 + r;
                int col = nt * 16 + arow;
                float v = fmaxf(acc[nt][r], 0.0f);
                unsigned short hi = f2bf(v);
                unsigned short lo = f2bf(v - bf2f(hi));
                h_hi[row * LDH + col] = hi;
                h_lo[row * LDH + col] = lo;
            }
    }

    // ---- output layer ----
    {
        const int obase = f * 4096;  // u16 elems
        const float* bof = bo + (size_t)f * NO;
        f32x4 acc2[2];
        for (int nt = 0; nt < 2; ++nt) {
            float bv = bof[nt * 16 + arow];
            acc2[nt] = (f32x4){bv, bv, bv, bv};
        }
        for (int kt = 0; kt < 4; ++kt) {
            const int kof = kt * 32 + kgrp * 8;
            bf16x8 a_hi = *(const bf16x8*)&h_hi[(r0 + arow) * LDH + kof];
            bf16x8 a_lo = *(const bf16x8*)&h_lo[(r0 + arow) * LDH + kof];
            for (int nt = 0; nt < 2; ++nt) {
                const int boff = obase + (nt * 16 + arow) * 128 + kof;
                bf16x8 b_hi = *(const bf16x8*)&wo_hi[boff];
                bf16x8 b_lo = *(const bf16x8*)&wo_lo[boff];
                acc2[nt] = __builtin_amdgcn_mfma_f32_16x16x32_bf16(a_hi, b_hi, acc2[nt], 0, 0, 0);
                acc2[nt] = __builtin_amdgcn_mfma_f32_16x16x32_bf16(a_lo, b_hi, acc2[nt], 0, 0, 0);
                acc2[nt] = __builtin_amdgcn_mfma_f32_16x16x32_bf16(a_hi, b_lo, acc2[nt], 0, 0, 0);
            }
        }
        for (int nt = 0; nt < 2; ++nt)
            for (int r = 0; r < 4; ++r) {
                int row = m0 + r0 + kgrp * 4 + r;
                int col = nt * 16 + arow;
                atomicAdd(&out[(size_t)row * NO + col], acc2[nt][r]);
            }
    }
}

extern "C" void kernel_launch(void* const* d_in, const int* in_sizes, int n_in,
                              void* d_out, int out_size, void* d_ws, size_t ws_size,
                              hipStream_t stream) {
    const float* x  = (const float*)d_in[0];
    const float* W1 = (const float*)d_in[1];
    const float* b1 = (const float*)d_in[2];
    const float* Wh = (const float*)d_in[3];
    const float* bh = (const float*)d_in[4];
    const float* Wo = (const float*)d_in[5];
    const float* bo = (const float*)d_in[6];
    float* out = (float*)d_out;
    unsigned short* ws = (unsigned short*)d_ws;

    zero_out_kernel<<<(BATCH * NO + 255) / 256, 256, 0, stream>>>(out, BATCH * NO);
    prep_weights<<<(WH_ELEMS / 2) / 256, 256, 0, stream>>>(Wh, Wo, ws);
    ngam_fused<<<NF * (BATCH / MT), 256, 0, stream>>>(x, W1, b1, bh, bo, ws, out);
}

// Round 4
// 211.907 us; speedup vs baseline: 2.8177x; 2.8177x over previous
//
#include <hip/hip_runtime.h>

#define BATCH 4096
#define NF 128
#define NW 128
#define NO 32
#define MT 128    // batch rows per block; 32 rows (2 m-tiles) per wave, wave-private
#define LDH 136   // h stride in u16 (272B rows: 16B-aligned, 2-way banks = free)

// d_ws layout (u16 elems): wh (fp16, [l,f][v][k]) | wo (fp16, [f][o][k])
#define WH_ELEMS (2 * 128 * 128 * 128)  // 4,194,304
#define WO_ELEMS (128 * 128 * 32)       //   524,288

typedef _Float16 f16x8 __attribute__((ext_vector_type(8)));
typedef float f32x4 __attribute__((ext_vector_type(4)));

static __device__ __forceinline__ unsigned short f2h(float f) {
    return __builtin_bit_cast(unsigned short, (_Float16)f);  // v_cvt_f16_f32, RNE
}

__global__ void zero_out_kernel(float* __restrict__ out, int n) {
    int i = blockIdx.x * blockDim.x + threadIdx.x;
    if (i < n) out[i] = 0.0f;
}

// Transpose + fp16-convert weights into ws. One element-pair per thread.
__global__ void prep_weights(const float* __restrict__ Wh, const float* __restrict__ Wo,
                             unsigned short* __restrict__ ws) {
    unsigned short* wh = ws;
    unsigned short* wo = ws + WH_ELEMS;
    int t = blockIdx.x * blockDim.x + threadIdx.x;
    if (t < WH_ELEMS / 2) {
        int kp = t & 63;          // k-pair
        int v  = (t >> 6) & 127;  // output col
        int lf = t >> 13;         // l*128+f
        size_t s = (size_t)lf * 16384;
        float g0 = Wh[s + (size_t)(2 * kp) * 128 + v];  // Wh[l,f,k,v]
        float g1 = Wh[s + (size_t)(2 * kp + 1) * 128 + v];
        size_t d = s + (size_t)v * 128 + 2 * kp;        // Wt[l,f,v,k]
        *(unsigned*)&wh[d] = (unsigned)f2h(g0) | ((unsigned)f2h(g1) << 16);
    }
    if (t < WO_ELEMS / 2) {
        int kp = t & 63;
        int o  = (t >> 6) & 31;
        int f  = t >> 11;
        size_t s = (size_t)f * 4096;
        float g0 = Wo[s + (size_t)(2 * kp) * 32 + o];   // Wo[f,k,o]
        float g1 = Wo[s + (size_t)(2 * kp + 1) * 32 + o];
        size_t d = s + (size_t)o * 128 + 2 * kp;        // WoT[f,o,k]
        *(unsigned*)&wo[d] = (unsigned)f2h(g0) | ((unsigned)f2h(g1) << 16);
    }
}

// Fused MLP chain, fp16 operands / fp32 accum. Each wave owns 32 rows
// end-to-end: NO barriers anywhere in the kernel.
__global__ __launch_bounds__(256, 4) void ngam_fused(
    const float* __restrict__ x, const float* __restrict__ W1,
    const float* __restrict__ b1, const float* __restrict__ bh,
    const float* __restrict__ bo, const unsigned short* __restrict__ ws,
    float* __restrict__ out) {
    __shared__ unsigned short h_sm[MT * LDH];
    const unsigned short* wh = ws;
    const unsigned short* wo = ws + WH_ELEMS;

    const int f    = blockIdx.x >> 5;        // 32 batch-tiles per feature
    const int m0   = (blockIdx.x & 31) * MT;
    const int tid  = threadIdx.x;
    const int wave = tid >> 6;
    const int lane = tid & 63;
    const int arow = lane & 15;  // A row / B col / C col
    const int kgrp = lane >> 4;  // k-group; C row-group
    const int r0   = wave * 32;  // this wave's private 32 rows

    // ---- layer 0: h = relu(x[:,f]*W1[f,:]+b1[f,:]), fp32 exact -> fp16 LDS ----
    // rows m = tid>>1 lie in [r0, r0+32) -> wave-private
    {
        int m = tid >> 1, c = tid & 1;
        float xv = x[(size_t)(m0 + m) * NF + f];
        for (int j = 0; j < 16; ++j) {
            int wq = c * 64 + j * 4;
            float4 w1 = *(const float4*)&W1[f * NW + wq];
            float4 bb = *(const float4*)&b1[f * NW + wq];
            float v0 = fmaxf(xv * w1.x + bb.x, 0.0f);
            float v1 = fmaxf(xv * w1.y + bb.y, 0.0f);
            float v2 = fmaxf(xv * w1.z + bb.z, 0.0f);
            float v3 = fmaxf(xv * w1.w + bb.w, 0.0f);
            *(unsigned*)&h_sm[m * LDH + wq]     = (unsigned)f2h(v0) | ((unsigned)f2h(v1) << 16);
            *(unsigned*)&h_sm[m * LDH + wq + 2] = (unsigned)f2h(v2) | ((unsigned)f2h(v3) << 16);
        }
    }

    // ---- hidden layers ----
    for (int l = 0; l < 2; ++l) {
        const int wbase = (l * NF + f) * 16384;  // u16 elems
        const float* bhl = bh + ((size_t)l * NF + f) * NW;
        f32x4 acc[2][8];
        for (int nt = 0; nt < 8; ++nt) {
            float bv = bhl[nt * 16 + arow];
            acc[0][nt] = (f32x4){bv, bv, bv, bv};
            acc[1][nt] = acc[0][nt];
        }
#pragma unroll
        for (int kt = 0; kt < 4; ++kt) {
            const int kof = kt * 32 + kgrp * 8;
            f16x8 a0 = *(const f16x8*)&h_sm[(r0 + arow) * LDH + kof];
            f16x8 a1 = *(const f16x8*)&h_sm[(r0 + 16 + arow) * LDH + kof];
#pragma unroll
            for (int nt = 0; nt < 8; ++nt) {
                f16x8 b = *(const f16x8*)&wh[wbase + (nt * 16 + arow) * 128 + kof];
                acc[0][nt] = __builtin_amdgcn_mfma_f32_16x16x32_f16(a0, b, acc[0][nt], 0, 0, 0);
                acc[1][nt] = __builtin_amdgcn_mfma_f32_16x16x32_f16(a1, b, acc[1][nt], 0, 0, 0);
            }
        }
        // relu + fp16 writeback; rows [r0, r0+32) wave-private
        for (int mt = 0; mt < 2; ++mt)
            for (int nt = 0; nt < 8; ++nt)
                for (int r = 0; r < 4; ++r) {
                    int row = r0 + mt * 16 + kgrp * 4 + r;
                    int col = nt * 16 + arow;
                    h_sm[row * LDH + col] = f2h(fmaxf(acc[mt][nt][r], 0.0f));
                }
    }

    // ---- output layer ----
    {
        const int obase = f * 4096;  // u16 elems
        const float* bof = bo + (size_t)f * NO;
        f32x4 acc2[2][2];
        for (int nt = 0; nt < 2; ++nt) {
            float bv = bof[nt * 16 + arow];
            acc2[0][nt] = (f32x4){bv, bv, bv, bv};
            acc2[1][nt] = acc2[0][nt];
        }
#pragma unroll
        for (int kt = 0; kt < 4; ++kt) {
            const int kof = kt * 32 + kgrp * 8;
            f16x8 a0 = *(const f16x8*)&h_sm[(r0 + arow) * LDH + kof];
            f16x8 a1 = *(const f16x8*)&h_sm[(r0 + 16 + arow) * LDH + kof];
#pragma unroll
            for (int nt = 0; nt < 2; ++nt) {
                f16x8 b = *(const f16x8*)&wo[obase + (nt * 16 + arow) * 128 + kof];
                acc2[0][nt] = __builtin_amdgcn_mfma_f32_16x16x32_f16(a0, b, acc2[0][nt], 0, 0, 0);
                acc2[1][nt] = __builtin_amdgcn_mfma_f32_16x16x32_f16(a1, b, acc2[1][nt], 0, 0, 0);
            }
        }
        for (int mt = 0; mt < 2; ++mt)
            for (int nt = 0; nt < 2; ++nt)
                for (int r = 0; r < 4; ++r) {
                    int row = m0 + r0 + mt * 16 + kgrp * 4 + r;
                    int col = nt * 16 + arow;
                    atomicAdd(&out[(size_t)row * NO + col], acc2[mt][nt][r]);
                }
    }
}

extern "C" void kernel_launch(void* const* d_in, const int* in_sizes, int n_in,
                              void* d_out, int out_size, void* d_ws, size_t ws_size,
                              hipStream_t stream) {
    const float* x  = (const float*)d_in[0];
    const float* W1 = (const float*)d_in[1];
    const float* b1 = (const float*)d_in[2];
    const float* Wh = (const float*)d_in[3];
    const float* bh = (const float*)d_in[4];
    const float* Wo = (const float*)d_in[5];
    const float* bo = (const float*)d_in[6];
    float* out = (float*)d_out;
    unsigned short* ws = (unsigned short*)d_ws;

    zero_out_kernel<<<(BATCH * NO + 255) / 256, 256, 0, stream>>>(out, BATCH * NO);
    prep_weights<<<(WH_ELEMS / 2) / 256, 256, 0, stream>>>(Wh, Wo, ws);
    ngam_fused<<<NF * (BATCH / MT), 256, 0, stream>>>(x, W1, b1, bh, bo, ws, out);
}

// Round 5
// 177.314 us; speedup vs baseline: 3.3674x; 1.1951x over previous
//
#include <hip/hip_runtime.h>

#define BATCH 4096
#define NF 128
#define NW 128
#define NO 32
#define MT 128    // batch rows per block
#define LDH 136   // h stride in u16 (272B rows: 16B-aligned, ~2-way banks = free)
#define FPB 2     // features per block (halves atomic traffic)

typedef _Float16 f16x8 __attribute__((ext_vector_type(8)));
typedef float f32x4 __attribute__((ext_vector_type(4)));

static __device__ __forceinline__ unsigned short f2h(float f) {
    return __builtin_bit_cast(unsigned short, (_Float16)f);  // v_cvt_f16_f32, RNE
}

__global__ void zero_out_kernel(float* __restrict__ out, int n) {
    int i = blockIdx.x * blockDim.x + threadIdx.x;
    if (i < n) out[i] = 0.0f;
}

// Fused MLP chain, fp16 operands / fp32 accum, weights read directly from fp32.
// Hidden layers: column-split (wave owns 32 output cols, B-frags in regs once
// per layer, sweeps all 8 m-tiles). Output layer: row-private. 2 features/block.
__global__ __launch_bounds__(256, 3) void ngam_fused(
    const float* __restrict__ x, const float* __restrict__ W1,
    const float* __restrict__ b1, const float* __restrict__ Wh,
    const float* __restrict__ bh, const float* __restrict__ Wo,
    const float* __restrict__ bo, float* __restrict__ out) {
    __shared__ __align__(16) unsigned short h_sm[MT * LDH];

    const int fpair = blockIdx.x >> 5;       // 0..63; blocks 0-31 share features
    const int m0    = (blockIdx.x & 31) * MT;
    const int tid   = threadIdx.x;
    const int wave  = tid >> 6;
    const int lane  = tid & 63;
    const int arow  = lane & 15;  // A row / B col / C col
    const int kgrp  = lane >> 4;  // k-group; C row-group
    const int r0    = wave * 32;  // wave's 32 rows (output) == wave's 32 cols (hidden)

    f32x4 oacc[2][2];  // output accumulator across features: [mt2][ntl]
    for (int a = 0; a < 2; ++a)
        for (int b = 0; b < 2; ++b) oacc[a][b] = (f32x4){0.f, 0.f, 0.f, 0.f};

    for (int fp = 0; fp < FPB; ++fp) {
        const int f = fpair + fp * (NF / FPB);

        // ---- layer 0: h = relu(x[:,f]*W1[f,:]+b1[f,:]), fp32 exact -> fp16 LDS ----
        {
            int m = tid >> 1, c = tid & 1;  // row m is wave-private (m>>5 == wave)
            float xv = x[(size_t)(m0 + m) * NF + f];
            const float* w1r = &W1[f * NW];
            const float* b1r = &b1[f * NW];
#pragma unroll
            for (int j = 0; j < 16; ++j) {
                int wq = c * 64 + j * 4;
                float4 w1 = *(const float4*)&w1r[wq];
                float4 bb = *(const float4*)&b1r[wq];
                float v0 = fmaxf(xv * w1.x + bb.x, 0.0f);
                float v1 = fmaxf(xv * w1.y + bb.y, 0.0f);
                float v2 = fmaxf(xv * w1.z + bb.z, 0.0f);
                float v3 = fmaxf(xv * w1.w + bb.w, 0.0f);
                *(unsigned*)&h_sm[m * LDH + wq]     = (unsigned)f2h(v0) | ((unsigned)f2h(v1) << 16);
                *(unsigned*)&h_sm[m * LDH + wq + 2] = (unsigned)f2h(v2) | ((unsigned)f2h(v3) << 16);
            }
        }
        __syncthreads();

        // ---- hidden layers (column-split) ----
#pragma unroll
        for (int l = 0; l < 2; ++l) {
            const float* Wl  = Wh + (size_t)(l * NF + f) * NW * NW;  // [k][v]
            const float* bhl = bh + (size_t)(l * NF + f) * NW;

            // B-fragments for this wave's 32 cols, loaded once, fp32->fp16
            f16x8 breg[2][4];
#pragma unroll
            for (int ntl = 0; ntl < 2; ++ntl) {
                const int v = r0 + ntl * 16 + arow;  // global col
#pragma unroll
                for (int kt = 0; kt < 4; ++kt) {
                    const int kb = kt * 32 + kgrp * 8;
                    f16x8 bf;
#pragma unroll
                    for (int j = 0; j < 8; ++j)
                        bf[j] = (_Float16)Wl[(size_t)(kb + j) * NW + v];
                    breg[ntl][kt] = bf;
                }
            }

            f32x4 acc[8][2];
#pragma unroll
            for (int ntl = 0; ntl < 2; ++ntl) {
                float bv = bhl[r0 + ntl * 16 + arow];
#pragma unroll
                for (int mt = 0; mt < 8; ++mt) acc[mt][ntl] = (f32x4){bv, bv, bv, bv};
            }
#pragma unroll
            for (int mt = 0; mt < 8; ++mt) {
#pragma unroll
                for (int kt = 0; kt < 4; ++kt) {
                    f16x8 a = *(const f16x8*)&h_sm[(mt * 16 + arow) * LDH + kt * 32 + kgrp * 8];
                    acc[mt][0] = __builtin_amdgcn_mfma_f32_16x16x32_f16(a, breg[0][kt], acc[mt][0], 0, 0, 0);
                    acc[mt][1] = __builtin_amdgcn_mfma_f32_16x16x32_f16(a, breg[1][kt], acc[mt][1], 0, 0, 0);
                }
            }
            __syncthreads();  // all waves done reading h
#pragma unroll
            for (int mt = 0; mt < 8; ++mt)
#pragma unroll
                for (int ntl = 0; ntl < 2; ++ntl)
#pragma unroll
                    for (int r = 0; r < 4; ++r)
                        h_sm[(mt * 16 + kgrp * 4 + r) * LDH + r0 + ntl * 16 + arow] =
                            f2h(fmaxf(acc[mt][ntl][r], 0.0f));
            __syncthreads();  // writeback visible
        }

        // ---- output layer (row-private: wave's own 32 rows, all 32 cols) ----
        {
            const float* Wof = Wo + (size_t)f * NW * NO;  // [k][o]
            const float* bof = bo + (size_t)f * NO;
            f16x8 ob[2][4];
#pragma unroll
            for (int ntl = 0; ntl < 2; ++ntl) {
                const int o = ntl * 16 + arow;
#pragma unroll
                for (int kt = 0; kt < 4; ++kt) {
                    const int kb = kt * 32 + kgrp * 8;
                    f16x8 bf;
#pragma unroll
                    for (int j = 0; j < 8; ++j)
                        bf[j] = (_Float16)Wof[(size_t)(kb + j) * NO + o];
                    ob[ntl][kt] = bf;
                }
            }
            f32x4 acc2[2][2];
#pragma unroll
            for (int ntl = 0; ntl < 2; ++ntl) {
                float bv = bof[ntl * 16 + arow];
                acc2[0][ntl] = (f32x4){bv, bv, bv, bv};
                acc2[1][ntl] = acc2[0][ntl];
            }
#pragma unroll
            for (int mt2 = 0; mt2 < 2; ++mt2) {
#pragma unroll
                for (int kt = 0; kt < 4; ++kt) {
                    f16x8 a = *(const f16x8*)&h_sm[(r0 + mt2 * 16 + arow) * LDH + kt * 32 + kgrp * 8];
                    acc2[mt2][0] = __builtin_amdgcn_mfma_f32_16x16x32_f16(a, ob[0][kt], acc2[mt2][0], 0, 0, 0);
                    acc2[mt2][1] = __builtin_amdgcn_mfma_f32_16x16x32_f16(a, ob[1][kt], acc2[mt2][1], 0, 0, 0);
                }
            }
#pragma unroll
            for (int mt2 = 0; mt2 < 2; ++mt2)
#pragma unroll
                for (int ntl = 0; ntl < 2; ++ntl) oacc[mt2][ntl] += acc2[mt2][ntl];
        }
        __syncthreads();  // h_sm reads done before next feature's layer-0 fill
    }

    // ---- single atomic accumulation over the feature dim ----
#pragma unroll
    for (int mt2 = 0; mt2 < 2; ++mt2)
#pragma unroll
        for (int ntl = 0; ntl < 2; ++ntl)
#pragma unroll
            for (int r = 0; r < 4; ++r) {
                int row = m0 + r0 + mt2 * 16 + kgrp * 4 + r;
                int col = ntl * 16 + arow;
                atomicAdd(&out[(size_t)row * NO + col], oacc[mt2][ntl][r]);
            }
}

extern "C" void kernel_launch(void* const* d_in, const int* in_sizes, int n_in,
                              void* d_out, int out_size, void* d_ws, size_t ws_size,
                              hipStream_t stream) {
    const float* x  = (const float*)d_in[0];
    const float* W1 = (const float*)d_in[1];
    const float* b1 = (const float*)d_in[2];
    const float* Wh = (const float*)d_in[3];
    const float* bh = (const float*)d_in[4];
    const float* Wo = (const float*)d_in[5];
    const float* bo = (const float*)d_in[6];
    float* out = (float*)d_out;

    zero_out_kernel<<<(BATCH * NO + 255) / 256, 256, 0, stream>>>(out, BATCH * NO);
    ngam_fused<<<(NF / FPB) * (BATCH / MT), 256, 0, stream>>>(x, W1, b1, Wh, bh, Wo, bo, out);
}

// Round 6
// 161.830 us; speedup vs baseline: 3.6897x; 1.0957x over previous
//
#include <hip/hip_runtime.h>

#define BATCH 4096
#define NF 128
#define NW 128
#define NO 32
#define MT 128    // batch rows per block
#define LDH 136   // h stride in u16 (272B rows: 16B-aligned)
#define FPB 2     // features per block

// d_ws (u16 elems): wh fp16 [l,f][v][k] | wo fp16 [f][o][k]  (k contiguous)
#define WH_ELEMS (2 * 128 * 128 * 128)
#define WO_ELEMS (128 * 128 * 32)

typedef _Float16 f16x8 __attribute__((ext_vector_type(8)));
typedef float f32x4 __attribute__((ext_vector_type(4)));

static __device__ __forceinline__ unsigned short f2h(float f) {
    return __builtin_bit_cast(unsigned short, (_Float16)f);  // RNE
}

__global__ void zero_out_kernel(float* __restrict__ out, int n) {
    int i = blockIdx.x * blockDim.x + threadIdx.x;
    if (i < n) out[i] = 0.0f;
}

// Transpose + fp16-convert weights into ws (verified in round 4).
__global__ void prep_weights(const float* __restrict__ Wh, const float* __restrict__ Wo,
                             unsigned short* __restrict__ ws) {
    unsigned short* wh = ws;
    unsigned short* wo = ws + WH_ELEMS;
    int t = blockIdx.x * blockDim.x + threadIdx.x;
    if (t < WH_ELEMS / 2) {
        int kp = t & 63;
        int v  = (t >> 6) & 127;
        int lf = t >> 13;
        size_t s = (size_t)lf * 16384;
        float g0 = Wh[s + (size_t)(2 * kp) * 128 + v];
        float g1 = Wh[s + (size_t)(2 * kp + 1) * 128 + v];
        size_t d = s + (size_t)v * 128 + 2 * kp;
        *(unsigned*)&wh[d] = (unsigned)f2h(g0) | ((unsigned)f2h(g1) << 16);
    }
    if (t < WO_ELEMS / 2) {
        int kp = t & 63;
        int o  = (t >> 6) & 31;
        int f  = t >> 11;
        size_t s = (size_t)f * 4096;
        float g0 = Wo[s + (size_t)(2 * kp) * 32 + o];
        float g1 = Wo[s + (size_t)(2 * kp + 1) * 32 + o];
        size_t d = s + (size_t)o * 128 + 2 * kp;
        *(unsigned*)&wo[d] = (unsigned)f2h(g0) | ((unsigned)f2h(g1) << 16);
    }
}

// Fused MLP chain: fp16 operands / fp32 accum. 4 waves in a 2x2 (row x col)
// split; per hidden layer each wave holds its 16 B-fragments in registers.
__global__ __launch_bounds__(256, 2) void ngam_fused(
    const float* __restrict__ x, const float* __restrict__ W1,
    const float* __restrict__ b1, const float* __restrict__ bh,
    const float* __restrict__ bo, const unsigned short* __restrict__ ws,
    float* __restrict__ out) {
    __shared__ __align__(16) unsigned short h_sm[MT * LDH];
    const unsigned short* wh = ws;
    const unsigned short* wo = ws + WH_ELEMS;

    const int fpair = blockIdx.x >> 5;
    const int m0    = (blockIdx.x & 31) * MT;
    const int tid   = threadIdx.x;
    const int wave  = tid >> 6;
    const int lane  = tid & 63;
    const int arow  = lane & 15;
    const int kgrp  = lane >> 4;
    const int wr    = wave >> 1;  // row-half owner (64 rows)
    const int wc    = wave & 1;   // col-half owner (64 cols)
    const int r0    = wave * 32;  // private rows for output stage

    f32x4 oacc[2][2];
    for (int a = 0; a < 2; ++a)
        for (int b = 0; b < 2; ++b) oacc[a][b] = (f32x4){0.f, 0.f, 0.f, 0.f};

    for (int fp = 0; fp < FPB; ++fp) {
        const int f = fpair + fp * (NF / FPB);

        // ---- preload layer-1 B fragments (16 x b128, independent) ----
        f16x8 B[4][4];  // [nt][kt]
        {
            const unsigned short* wp = wh + (size_t)(0 * NF + f) * 16384;
#pragma unroll
            for (int nt = 0; nt < 4; ++nt)
#pragma unroll
                for (int kt = 0; kt < 4; ++kt)
                    B[nt][kt] = *(const f16x8*)&wp[(wc * 64 + nt * 16 + arow) * 128 + kt * 32 + kgrp * 8];
        }

        // ---- layer 0: h = relu(x*W1+b1), fp32 exact -> fp16 LDS ----
        {
            int m = tid >> 1, c = tid & 1;
            float xv = x[(size_t)(m0 + m) * NF + f];
            const float* w1r = &W1[f * NW];
            const float* b1r = &b1[f * NW];
#pragma unroll
            for (int j = 0; j < 16; ++j) {
                int wq = c * 64 + j * 4;
                float4 w1 = *(const float4*)&w1r[wq];
                float4 bb = *(const float4*)&b1r[wq];
                float v0 = fmaxf(xv * w1.x + bb.x, 0.0f);
                float v1 = fmaxf(xv * w1.y + bb.y, 0.0f);
                float v2 = fmaxf(xv * w1.z + bb.z, 0.0f);
                float v3 = fmaxf(xv * w1.w + bb.w, 0.0f);
                *(unsigned*)&h_sm[m * LDH + wq]     = (unsigned)f2h(v0) | ((unsigned)f2h(v1) << 16);
                *(unsigned*)&h_sm[m * LDH + wq + 2] = (unsigned)f2h(v2) | ((unsigned)f2h(v3) << 16);
            }
        }
        __syncthreads();

        // ---- two hidden layers, manually unrolled so next B-loads overlap ----
#pragma unroll
        for (int l = 0; l < 2; ++l) {
            const float* bhl = bh + (size_t)(l * NF + f) * NW;
            f32x4 acc[4][4];  // [mt][nt]
#pragma unroll
            for (int nt = 0; nt < 4; ++nt) {
                float bv = bhl[wc * 64 + nt * 16 + arow];
#pragma unroll
                for (int mt = 0; mt < 4; ++mt) acc[mt][nt] = (f32x4){bv, bv, bv, bv};
            }
#pragma unroll
            for (int mt = 0; mt < 4; ++mt) {
#pragma unroll
                for (int kt = 0; kt < 4; ++kt) {
                    f16x8 a = *(const f16x8*)&h_sm[(wr * 64 + mt * 16 + arow) * LDH + kt * 32 + kgrp * 8];
#pragma unroll
                    for (int nt = 0; nt < 4; ++nt)
                        acc[mt][nt] = __builtin_amdgcn_mfma_f32_16x16x32_f16(a, B[nt][kt], acc[mt][nt], 0, 0, 0);
                }
            }
            // issue next stage's B loads now: latency hides under barrier+writeback
            if (l == 0) {
                const unsigned short* wp = wh + (size_t)(1 * NF + f) * 16384;
#pragma unroll
                for (int nt = 0; nt < 4; ++nt)
#pragma unroll
                    for (int kt = 0; kt < 4; ++kt)
                        B[nt][kt] = *(const f16x8*)&wp[(wc * 64 + nt * 16 + arow) * 128 + kt * 32 + kgrp * 8];
            }
            __syncthreads();  // all waves done reading h
#pragma unroll
            for (int mt = 0; mt < 4; ++mt)
#pragma unroll
                for (int nt = 0; nt < 4; ++nt)
#pragma unroll
                    for (int r = 0; r < 4; ++r)
                        h_sm[(wr * 64 + mt * 16 + kgrp * 4 + r) * LDH + wc * 64 + nt * 16 + arow] =
                            f2h(fmaxf(acc[mt][nt][r], 0.0f));
            __syncthreads();  // writeback visible
        }

        // ---- output layer (row-private: wave's 32 rows, 32 cols) ----
        {
            const unsigned short* wp = wo + (size_t)f * 4096;
            const float* bof = bo + (size_t)f * NO;
            f16x8 Bo[2][4];
#pragma unroll
            for (int ntl = 0; ntl < 2; ++ntl)
#pragma unroll
                for (int kt = 0; kt < 4; ++kt)
                    Bo[ntl][kt] = *(const f16x8*)&wp[(ntl * 16 + arow) * 128 + kt * 32 + kgrp * 8];
            f32x4 acc2[2][2];
#pragma unroll
            for (int ntl = 0; ntl < 2; ++ntl) {
                float bv = bof[ntl * 16 + arow];
                acc2[0][ntl] = (f32x4){bv, bv, bv, bv};
                acc2[1][ntl] = acc2[0][ntl];
            }
#pragma unroll
            for (int mt2 = 0; mt2 < 2; ++mt2) {
#pragma unroll
                for (int kt = 0; kt < 4; ++kt) {
                    f16x8 a = *(const f16x8*)&h_sm[(r0 + mt2 * 16 + arow) * LDH + kt * 32 + kgrp * 8];
                    acc2[mt2][0] = __builtin_amdgcn_mfma_f32_16x16x32_f16(a, Bo[0][kt], acc2[mt2][0], 0, 0, 0);
                    acc2[mt2][1] = __builtin_amdgcn_mfma_f32_16x16x32_f16(a, Bo[1][kt], acc2[mt2][1], 0, 0, 0);
                }
            }
#pragma unroll
            for (int mt2 = 0; mt2 < 2; ++mt2)
#pragma unroll
                for (int ntl = 0; ntl < 2; ++ntl) oacc[mt2][ntl] += acc2[mt2][ntl];
        }
        __syncthreads();  // h_sm reads done before next feature's layer-0 fill
    }

    // ---- atomic accumulation over features ----
#pragma unroll
    for (int mt2 = 0; mt2 < 2; ++mt2)
#pragma unroll
        for (int ntl = 0; ntl < 2; ++ntl)
#pragma unroll
            for (int r = 0; r < 4; ++r) {
                int row = m0 + r0 + mt2 * 16 + kgrp * 4 + r;
                int col = ntl * 16 + arow;
                atomicAdd(&out[(size_t)row * NO + col], oacc[mt2][ntl][r]);
            }
}

extern "C" void kernel_launch(void* const* d_in, const int* in_sizes, int n_in,
                              void* d_out, int out_size, void* d_ws, size_t ws_size,
                              hipStream_t stream) {
    const float* x  = (const float*)d_in[0];
    const float* W1 = (const float*)d_in[1];
    const float* b1 = (const float*)d_in[2];
    const float* Wh = (const float*)d_in[3];
    const float* bh = (const float*)d_in[4];
    const float* Wo = (const float*)d_in[5];
    const float* bo = (const float*)d_in[6];
    float* out = (float*)d_out;
    unsigned short* ws = (unsigned short*)d_ws;

    zero_out_kernel<<<(BATCH * NO + 255) / 256, 256, 0, stream>>>(out, BATCH * NO);
    prep_weights<<<(WH_ELEMS / 2) / 256, 256, 0, stream>>>(Wh, Wo, ws);
    ngam_fused<<<(NF / FPB) * (BATCH / MT), 256, 0, stream>>>(x, W1, b1, bh, bo, ws, out);
}

// Round 7
// 149.326 us; speedup vs baseline: 3.9986x; 1.0837x over previous
//
#include <hip/hip_runtime.h>

#define BATCH 4096
#define NF 128
#define NW 128
#define NO 32
#define MT 128    // batch rows per block
#define LDH 136   // h stride in u16 (272B rows: 16B-aligned)

// d_ws (u16 elems): wh fp16 [l,f][v][k] | wo fp16 [f][o][k]  (k contiguous)
#define WH_ELEMS (2 * 128 * 128 * 128)
#define WO_ELEMS (128 * 128 * 32)

typedef _Float16 f16x8 __attribute__((ext_vector_type(8)));
typedef float f32x4 __attribute__((ext_vector_type(4)));

static __device__ __forceinline__ unsigned short f2h(float f) {
    return __builtin_bit_cast(unsigned short, (_Float16)f);  // RNE
}

__global__ void zero_out_kernel(float* __restrict__ out, int n) {
    int i = blockIdx.x * blockDim.x + threadIdx.x;
    if (i < n) out[i] = 0.0f;
}

// Coalesced transpose + fp16 convert via LDS (stride 138 u16: conflict-free).
// Blocks 0..255: Wh matrix lf=b ([k][v] -> [v][k]); blocks 256..383: Wo f=b-256.
__global__ __launch_bounds__(256) void prep_weights2(
    const float* __restrict__ Wh, const float* __restrict__ Wo,
    unsigned short* __restrict__ ws) {
    __shared__ unsigned short t_sm[128 * 138];
    unsigned short* wh = ws;
    unsigned short* wo = ws + WH_ELEMS;
    const int b = blockIdx.x;
    const int tid = threadIdx.x;
    if (b < 256) {
        const float* src = Wh + (size_t)b * 16384;  // [k][v]
        for (int i = tid; i < 16384; i += 256) {
            int k = i >> 7, v = i & 127;
            t_sm[v * 138 + k] = f2h(src[i]);  // coalesced read
        }
        __syncthreads();
        unsigned short* dst = wh + (size_t)b * 16384;  // [v][k]
        for (int i = tid; i < 8192; i += 256) {
            int v = i >> 6, kp = i & 63;
            unsigned lo = t_sm[v * 138 + 2 * kp];
            unsigned hi = t_sm[v * 138 + 2 * kp + 1];
            *(unsigned*)&dst[v * 128 + 2 * kp] = lo | (hi << 16);  // coalesced write
        }
    } else {
        const int f = b - 256;
        const float* src = Wo + (size_t)f * 4096;  // [k][o]
        for (int i = tid; i < 4096; i += 256) {
            int k = i >> 5, o = i & 31;
            t_sm[o * 138 + k] = f2h(src[i]);
        }
        __syncthreads();
        unsigned short* dst = wo + (size_t)f * 4096;  // [o][k]
        for (int i = tid; i < 2048; i += 256) {
            int o = i >> 6, kp = i & 63;
            unsigned lo = t_sm[o * 138 + 2 * kp];
            unsigned hi = t_sm[o * 138 + 2 * kp + 1];
            *(unsigned*)&dst[o * 128 + 2 * kp] = lo | (hi << 16);
        }
    }
}

// Fused MLP chain: fp16 operands / fp32 accum. 2x2 wave split; hidden-layer B
// held in registers in two 32-col halves (register budget for 4 waves/SIMD).
__global__ __launch_bounds__(256, 4) void ngam_fused(
    const float* __restrict__ x, const float* __restrict__ W1,
    const float* __restrict__ b1, const float* __restrict__ bh,
    const float* __restrict__ bo, const unsigned short* __restrict__ ws,
    float* __restrict__ out) {
    __shared__ __align__(16) unsigned short h_sm[MT * LDH];
    const unsigned short* wh = ws;
    const unsigned short* wo = ws + WH_ELEMS;

    const int f    = blockIdx.x >> 5;        // feature
    const int m0   = (blockIdx.x & 31) * MT; // batch tile
    const int tid  = threadIdx.x;
    const int wave = tid >> 6;
    const int lane = tid & 63;
    const int arow = lane & 15;
    const int kgrp = lane >> 4;
    const int wr   = wave >> 1;  // row-half (64 rows)
    const int wc   = wave & 1;   // col-half (64 cols)
    const int r0   = wave * 32;  // private rows for output stage

    // ---- layer 0: h = relu(x*W1+b1), fp32 exact -> fp16 LDS ----
    {
        int m = tid >> 1, c = tid & 1;
        float xv = x[(size_t)(m0 + m) * NF + f];
        const float* w1r = &W1[f * NW];
        const float* b1r = &b1[f * NW];
#pragma unroll
        for (int j = 0; j < 16; ++j) {
            int wq = c * 64 + j * 4;
            float4 w1 = *(const float4*)&w1r[wq];
            float4 bb = *(const float4*)&b1r[wq];
            float v0 = fmaxf(xv * w1.x + bb.x, 0.0f);
            float v1 = fmaxf(xv * w1.y + bb.y, 0.0f);
            float v2 = fmaxf(xv * w1.z + bb.z, 0.0f);
            float v3 = fmaxf(xv * w1.w + bb.w, 0.0f);
            *(unsigned*)&h_sm[m * LDH + wq]     = (unsigned)f2h(v0) | ((unsigned)f2h(v1) << 16);
            *(unsigned*)&h_sm[m * LDH + wq + 2] = (unsigned)f2h(v2) | ((unsigned)f2h(v3) << 16);
        }
    }
    __syncthreads();

    // ---- two hidden layers ----
#pragma unroll
    for (int l = 0; l < 2; ++l) {
        const unsigned short* wp = wh + (size_t)(l * NF + f) * 16384;
        const float* bhl = bh + (size_t)(l * NF + f) * NW;
        f32x4 acc[4][4];  // [mt][nt]
#pragma unroll
        for (int nt = 0; nt < 4; ++nt) {
            float bv = bhl[wc * 64 + nt * 16 + arow];
#pragma unroll
            for (int mt = 0; mt < 4; ++mt) acc[mt][nt] = (f32x4){bv, bv, bv, bv};
        }
#pragma unroll
        for (int nth = 0; nth < 2; ++nth) {
            f16x8 Bf[2][4];  // 32-col half of B, 8 x b128
#pragma unroll
            for (int j = 0; j < 2; ++j)
#pragma unroll
                for (int kt = 0; kt < 4; ++kt)
                    Bf[j][kt] = *(const f16x8*)&wp[(wc * 64 + nth * 32 + j * 16 + arow) * 128 + kt * 32 + kgrp * 8];
#pragma unroll
            for (int mt = 0; mt < 4; ++mt) {
#pragma unroll
                for (int kt = 0; kt < 4; ++kt) {
                    f16x8 a = *(const f16x8*)&h_sm[(wr * 64 + mt * 16 + arow) * LDH + kt * 32 + kgrp * 8];
                    acc[mt][nth * 2 + 0] = __builtin_amdgcn_mfma_f32_16x16x32_f16(a, Bf[0][kt], acc[mt][nth * 2 + 0], 0, 0, 0);
                    acc[mt][nth * 2 + 1] = __builtin_amdgcn_mfma_f32_16x16x32_f16(a, Bf[1][kt], acc[mt][nth * 2 + 1], 0, 0, 0);
                }
            }
        }
        __syncthreads();  // all waves done reading h
#pragma unroll
        for (int mt = 0; mt < 4; ++mt)
#pragma unroll
            for (int nt = 0; nt < 4; ++nt)
#pragma unroll
                for (int r = 0; r < 4; ++r)
                    h_sm[(wr * 64 + mt * 16 + kgrp * 4 + r) * LDH + wc * 64 + nt * 16 + arow] =
                        f2h(fmaxf(acc[mt][nt][r], 0.0f));
        __syncthreads();  // writeback visible
    }

    // ---- output layer (row-private: wave's 32 rows, 32 cols) + atomics ----
    {
        const unsigned short* wop = wo + (size_t)f * 4096;
        const float* bof = bo + (size_t)f * NO;
        f16x8 Bo[2][4];
#pragma unroll
        for (int ntl = 0; ntl < 2; ++ntl)
#pragma unroll
            for (int kt = 0; kt < 4; ++kt)
                Bo[ntl][kt] = *(const f16x8*)&wop[(ntl * 16 + arow) * 128 + kt * 32 + kgrp * 8];
        f32x4 acc2[2][2];
#pragma unroll
        for (int ntl = 0; ntl < 2; ++ntl) {
            float bv = bof[ntl * 16 + arow];
            acc2[0][ntl] = (f32x4){bv, bv, bv, bv};
            acc2[1][ntl] = acc2[0][ntl];
        }
#pragma unroll
        for (int mt2 = 0; mt2 < 2; ++mt2) {
#pragma unroll
            for (int kt = 0; kt < 4; ++kt) {
                f16x8 a = *(const f16x8*)&h_sm[(r0 + mt2 * 16 + arow) * LDH + kt * 32 + kgrp * 8];
                acc2[mt2][0] = __builtin_amdgcn_mfma_f32_16x16x32_f16(a, Bo[0][kt], acc2[mt2][0], 0, 0, 0);
                acc2[mt2][1] = __builtin_amdgcn_mfma_f32_16x16x32_f16(a, Bo[1][kt], acc2[mt2][1], 0, 0, 0);
            }
        }
#pragma unroll
        for (int mt2 = 0; mt2 < 2; ++mt2)
#pragma unroll
            for (int ntl = 0; ntl < 2; ++ntl)
#pragma unroll
                for (int r = 0; r < 4; ++r) {
                    int row = m0 + r0 + mt2 * 16 + kgrp * 4 + r;
                    int col = ntl * 16 + arow;
                    atomicAdd(&out[(size_t)row * NO + col], acc2[mt2][ntl][r]);
                }
    }
}

extern "C" void kernel_launch(void* const* d_in, const int* in_sizes, int n_in,
                              void* d_out, int out_size, void* d_ws, size_t ws_size,
                              hipStream_t stream) {
    const float* x  = (const float*)d_in[0];
    const float* W1 = (const float*)d_in[1];
    const float* b1 = (const float*)d_in[2];
    const float* Wh = (const float*)d_in[3];
    const float* bh = (const float*)d_in[4];
    const float* Wo = (const float*)d_in[5];
    const float* bo = (const float*)d_in[6];
    float* out = (float*)d_out;
    unsigned short* ws = (unsigned short*)d_ws;

    zero_out_kernel<<<(BATCH * NO + 255) / 256, 256, 0, stream>>>(out, BATCH * NO);
    prep_weights2<<<384, 256, 0, stream>>>(Wh, Wo, ws);
    ngam_fused<<<NF * (BATCH / MT), 256, 0, stream>>>(x, W1, b1, bh, bo, ws, out);
}